// Round 9
// baseline (71422.430 us; speedup 1.0000x reference)
//
#include <hip/hip_runtime.h>

#define T_LEN 131072
#define HDIM  100
#define KPAD  112            // 100 h | 5 x | 1 bias-one | 6 zero
#define NROWS 400
#define NTHR  448
#define LOG2E 1.4426950408889634f

typedef __attribute__((ext_vector_type(2))) float f32x2;

// R9: weight residency via the R3-proven load pattern.
// A prep kernel builds the augmented, PRE-SCALED Waug[400][112] in d_ws:
//   cols 0..99 = W_hh row, 100..104 = W_ih row, 105 = b_ih+b_hh, 106..111 = 0,
//   row scaled by log2e (2*log2e for tanh rows 200..299).
// The main kernel loads its slice as 56 PLAIN CONTIGUOUS f32x2 loads from a
// __restrict pointer, used RAW in v_pk_fma — the only pattern that ever stayed
// register-resident (R3: VGPR=224). Branchy/scaled/volatile variants were all
// demoted by the scheduler/RA (R4/R6/R7/R8: VGPR 140/80/84/88).
// Loop body (verified absmax=0 since R6): 7 ds_read_b128 h-slice, 28 v_pk_fma,
// 2-step quad DPP butterfly, replicated cell update, lane0 writes h, lanes<5
// write x_{t+1}, ONE barrier (double-buffered LDS).

template <int PAT>
__device__ __forceinline__ float qdpp(float v) {
    return __int_as_float(__builtin_amdgcn_mov_dpp(__float_as_int(v), PAT, 0xf, 0xf, true));
}

__global__ __launch_bounds__(256, 1)
void lstm_prep_kernel(const float* __restrict__ W_ih,
                      const float* __restrict__ W_hh,
                      const float* __restrict__ b_ih,
                      const float* __restrict__ b_hh,
                      float* __restrict__ ws)
{
    const int idx = blockIdx.x * 256 + threadIdx.x;
    if (idx >= NROWS * KPAD) return;
    const int row = idx / KPAD;
    const int col = idx - row * KPAD;
    const float sc = ((row >= 2 * HDIM) && (row < 3 * HDIM)) ? 2.f * LOG2E : LOG2E;
    float wv;
    if      (col < HDIM)      wv = W_hh[row * HDIM + col];
    else if (col < HDIM + 5)  wv = W_ih[row * 5 + (col - HDIM)];
    else if (col == HDIM + 5) wv = b_ih[row] + b_hh[row];
    else                      wv = 0.f;
    ws[idx] = wv * sc;
}

__global__ __launch_bounds__(NTHR, 1)
void lstm_seq_kernel(const float* __restrict__ input_seq,
                     const float* __restrict__ ws,
                     const float* __restrict__ W_lin,
                     const float* __restrict__ b_lin,
                     float* __restrict__ out)
{
    __shared__ __align__(16) float hbuf[2][KPAD];

    const int tid = threadIdx.x;
    const int j   = tid >> 2;            // quad id / hidden index 0..111
    const int g   = tid & 3;             // K-slice id
    const bool act = j < HDIM;
    const int je  = act ? j : 0;
    const int cb  = 28 * g;              // first col of this lane's slice

    // ---- 56 named f32x2 weights: PLAIN contiguous loads, nothing else ----
    const f32x2* __restrict__ wr0 = (const f32x2*)(ws + (0 * HDIM + je) * KPAD + cb);
    const f32x2* __restrict__ wr1 = (const f32x2*)(ws + (1 * HDIM + je) * KPAD + cb);
    const f32x2* __restrict__ wr2 = (const f32x2*)(ws + (2 * HDIM + je) * KPAD + cb);
    const f32x2* __restrict__ wr3 = (const f32x2*)(ws + (3 * HDIM + je) * KPAD + cb);
#define WLD(v, k) const f32x2 w##v##_##k = wr##v[k];
#define WROW(v) \
    WLD(v,0)  WLD(v,1)  WLD(v,2)  WLD(v,3)  WLD(v,4)  WLD(v,5)  WLD(v,6) \
    WLD(v,7)  WLD(v,8)  WLD(v,9)  WLD(v,10) WLD(v,11) WLD(v,12) WLD(v,13)
    WROW(0) WROW(1) WROW(2) WROW(3)
#undef WROW
#undef WLD

    // ---- init LDS: h=0 both buffers, x_0 in buf0, bias-one in both ----
    if (tid < 2 * KPAD) ((float*)hbuf)[tid] = 0.f;
    __syncthreads();
    if (tid < 5) hbuf[0][HDIM + tid] = input_seq[tid];
    if (tid == 5) { hbuf[0][HDIM + 5] = 1.f; hbuf[1][HDIM + 5] = 1.f; }
    __syncthreads();

    float c = 0.f;                       // cell state, replicated in the quad

    for (int t = 0; t < T_LEN; ++t) {
        // prefetch next x (5 lanes), latency hidden under the matvec
        float xn = 0.f;
        if (tid < 5) {
            const int tn = (t + 1 < T_LEN) ? (t + 1) : (T_LEN - 1);
            xn = input_seq[tn * 5 + tid];
        }

        // h-slice: 7 x ds_read_b128 (4 distinct 16B segments/wave -> conflict-free)
        const float4* __restrict__ hp = (const float4*)(hbuf[t & 1] + cb);
        const float4 q0 = hp[0], q1 = hp[1], q2 = hp[2], q3 = hp[3];
        const float4 q4 = hp[4], q5 = hp[5], q6 = hp[6];

        // 4 gate-row partials, 8 accumulators (ILP), packed fp32 fma
        f32x2 p0a = f32x2{0.f, 0.f}, p0b = f32x2{0.f, 0.f};
        f32x2 p1a = f32x2{0.f, 0.f}, p1b = f32x2{0.f, 0.f};
        f32x2 p2a = f32x2{0.f, 0.f}, p2b = f32x2{0.f, 0.f};
        f32x2 p3a = f32x2{0.f, 0.f}, p3b = f32x2{0.f, 0.f};
#define FMQ(Q, KA, KB) {                                     \
        const f32x2 hA = f32x2{Q.x, Q.y};                    \
        const f32x2 hB = f32x2{Q.z, Q.w};                    \
        p0a = hA * w0_##KA + p0a;  p0b = hB * w0_##KB + p0b; \
        p1a = hA * w1_##KA + p1a;  p1b = hB * w1_##KB + p1b; \
        p2a = hA * w2_##KA + p2a;  p2b = hB * w2_##KB + p2b; \
        p3a = hA * w3_##KA + p3a;  p3b = hB * w3_##KB + p3b; }
        FMQ(q0, 0, 1)  FMQ(q1, 2, 3)  FMQ(q2, 4, 5)  FMQ(q3, 6, 7)
        FMQ(q4, 8, 9)  FMQ(q5, 10, 11) FMQ(q6, 12, 13)
#undef FMQ
        float p0 = (p0a.x + p0a.y) + (p0b.x + p0b.y);
        float p1 = (p1a.x + p1a.y) + (p1b.x + p1b.y);
        float p2 = (p2a.x + p2a.y) + (p2b.x + p2b.y);
        float p3 = (p3a.x + p3a.y) + (p3b.x + p3b.y);

        // quad butterfly: after xor1+xor2 every lane holds full z0..z3
        p0 += qdpp<0xB1>(p0); p1 += qdpp<0xB1>(p1);   // quad_perm(1,0,3,2)
        p2 += qdpp<0xB1>(p2); p3 += qdpp<0xB1>(p3);
        p0 += qdpp<0x4E>(p0); p1 += qdpp<0x4E>(p1);   // quad_perm(2,3,0,1)
        p2 += qdpp<0x4E>(p2); p3 += qdpp<0x4E>(p3);

        // gates (rows pre-scaled: sigmoid rows by log2e, tanh row by 2log2e)
        const float si = __builtin_amdgcn_rcpf(1.f + __builtin_amdgcn_exp2f(-p0));
        const float sf = __builtin_amdgcn_rcpf(1.f + __builtin_amdgcn_exp2f(-p1));
        const float gg = fmaf(2.f, __builtin_amdgcn_rcpf(1.f + __builtin_amdgcn_exp2f(-p2)), -1.f);
        const float so = __builtin_amdgcn_rcpf(1.f + __builtin_amdgcn_exp2f(-p3));

        // cell update (replicated across the quad's 4 lanes)
        c = fmaf(sf, c, si * gg);
        const float th = fmaf(2.f, __builtin_amdgcn_rcpf(1.f + __builtin_amdgcn_exp2f(c * (-2.f * LOG2E))), -1.f);
        const float hv = so * th;

        float* __restrict__ hn = hbuf[(t + 1) & 1];
        if ((g == 0) & act) hn[j] = hv;
        if (tid < 5) hn[HDIM + tid] = xn;
        __syncthreads();                 // single barrier per step
    }

    // epilogue: out = b_lin + W_lin . h_T   (T_LEN even -> h_T in hbuf[0])
    if (tid == 0) {
        float acc = b_lin[0];
        #pragma unroll
        for (int k = 0; k < HDIM; ++k) acc += W_lin[k] * hbuf[0][k];
        out[0] = acc;
    }
}

extern "C" void kernel_launch(void* const* d_in, const int* in_sizes, int n_in,
                              void* d_out, int out_size, void* d_ws, size_t ws_size,
                              hipStream_t stream) {
    const float* input_seq = (const float*)d_in[0];
    const float* W_ih      = (const float*)d_in[1];
    const float* W_hh      = (const float*)d_in[2];
    const float* b_ih      = (const float*)d_in[3];
    const float* b_hh      = (const float*)d_in[4];
    const float* W_lin     = (const float*)d_in[5];
    const float* b_lin     = (const float*)d_in[6];
    float* out = (float*)d_out;
    float* ws  = (float*)d_ws;           // needs 400*112*4 = 179,200 B

    const int nprep = NROWS * KPAD;
    lstm_prep_kernel<<<(nprep + 255) / 256, 256, 0, stream>>>(W_ih, W_hh, b_ih, b_hh, ws);
    lstm_seq_kernel<<<1, NTHR, 0, stream>>>(input_seq, ws, W_lin, b_lin, out);
}

// Round 11
// 69986.768 us; speedup vs baseline: 1.0205x; 1.0205x over previous
//
#include <hip/hip_runtime.h>

#define T_LEN 131072
#define HDIM  100
#define KPAD  112            // 100 h | 5 x | 1 bias-one | 6 zero
#define NROWS 400
#define NTHR  448
#define LOG2E 1.4426950408889634f

typedef __attribute__((ext_vector_type(2))) float f32x2;

// R11 = R10 with the asm pin applied to SCALAR floats (float4 tied asm
// operands are unsupported: "tied indirect register inputs").
// Residency scheme: (a) amdgpu_waves_per_eu(1,2) caps the occupancy target
// (VGPR budget 256; the 7-wave workgroup needs 2/EU anyway); (b) each of the
// 112 weight floats passes through an asm identity -> non-rematerializable.
// Structure = R9 (verified absmax=0): prep kernel builds pre-scaled augmented
// Waug[400][112] in d_ws; main loop: 7 ds_read_b128 h-slice, 56 v_pk_fma,
// 2-step quad DPP butterfly, replicated cell update, ONE barrier.

template <int PAT>
__device__ __forceinline__ float qdpp(float v) {
    return __int_as_float(__builtin_amdgcn_mov_dpp(__float_as_int(v), PAT, 0xf, 0xf, true));
}

__global__ __launch_bounds__(256, 1)
void lstm_prep_kernel(const float* __restrict__ W_ih,
                      const float* __restrict__ W_hh,
                      const float* __restrict__ b_ih,
                      const float* __restrict__ b_hh,
                      float* __restrict__ ws)
{
    const int idx = blockIdx.x * 256 + threadIdx.x;
    if (idx >= NROWS * KPAD) return;
    const int row = idx / KPAD;
    const int col = idx - row * KPAD;
    const float sc = ((row >= 2 * HDIM) && (row < 3 * HDIM)) ? 2.f * LOG2E : LOG2E;
    float wv;
    if      (col < HDIM)      wv = W_hh[row * HDIM + col];
    else if (col < HDIM + 5)  wv = W_ih[row * 5 + (col - HDIM)];
    else if (col == HDIM + 5) wv = b_ih[row] + b_hh[row];
    else                      wv = 0.f;
    ws[idx] = wv * sc;
}

__global__
__attribute__((amdgpu_flat_work_group_size(NTHR, NTHR)))
__attribute__((amdgpu_waves_per_eu(1, 2)))
void lstm_seq_kernel(const float* __restrict__ input_seq,
                     const float* __restrict__ ws,
                     const float* __restrict__ W_lin,
                     const float* __restrict__ b_lin,
                     float* __restrict__ out)
{
    __shared__ __align__(16) float hbuf[2][KPAD];

    const int tid = threadIdx.x;
    const int j   = tid >> 2;            // quad id / hidden index 0..111
    const int g   = tid & 3;             // K-slice id
    const bool act = j < HDIM;
    const int je  = act ? j : 0;
    const int cb  = 28 * g;              // first col of this lane's slice

    // ---- weights: plain contiguous float4 loads, then SCALAR asm pins ----
    const float4* __restrict__ wr0 = (const float4*)(ws + (0 * HDIM + je) * KPAD + cb);
    const float4* __restrict__ wr1 = (const float4*)(ws + (1 * HDIM + je) * KPAD + cb);
    const float4* __restrict__ wr2 = (const float4*)(ws + (2 * HDIM + je) * KPAD + cb);
    const float4* __restrict__ wr3 = (const float4*)(ws + (3 * HDIM + je) * KPAD + cb);
#define WLD(v, k)                                                   \
    float4 t##v##_##k = wr##v[k];                                   \
    float w##v##_##k##x = t##v##_##k.x; asm("" : "+v"(w##v##_##k##x)); \
    float w##v##_##k##y = t##v##_##k.y; asm("" : "+v"(w##v##_##k##y)); \
    float w##v##_##k##z = t##v##_##k.z; asm("" : "+v"(w##v##_##k##z)); \
    float w##v##_##k##w = t##v##_##k.w; asm("" : "+v"(w##v##_##k##w));
#define WROW(v) WLD(v,0) WLD(v,1) WLD(v,2) WLD(v,3) WLD(v,4) WLD(v,5) WLD(v,6)
    WROW(0) WROW(1) WROW(2) WROW(3)
#undef WROW
#undef WLD

    // ---- init LDS: h=0 both buffers, x_0 in buf0, bias-one in both ----
    if (tid < 2 * KPAD) ((float*)hbuf)[tid] = 0.f;
    __syncthreads();
    if (tid < 5) hbuf[0][HDIM + tid] = input_seq[tid];
    if (tid == 5) { hbuf[0][HDIM + 5] = 1.f; hbuf[1][HDIM + 5] = 1.f; }
    __syncthreads();

    float c = 0.f;                       // cell state, replicated in the quad

    for (int t = 0; t < T_LEN; ++t) {
        // prefetch next x (5 lanes), latency hidden under the matvec
        float xn = 0.f;
        if (tid < 5) {
            const int tn = (t + 1 < T_LEN) ? (t + 1) : (T_LEN - 1);
            xn = input_seq[tn * 5 + tid];
        }

        // h-slice: 7 x ds_read_b128 (4 distinct 16B segments/wave -> conflict-free)
        const float4* __restrict__ hp = (const float4*)(hbuf[t & 1] + cb);
        const float4 q0 = hp[0], q1 = hp[1], q2 = hp[2], q3 = hp[3];
        const float4 q4 = hp[4], q5 = hp[5], q6 = hp[6];

        // 4 gate-row partials, 8 accumulators (ILP), packed fp32 fma
        f32x2 p0a = f32x2{0.f, 0.f}, p0b = f32x2{0.f, 0.f};
        f32x2 p1a = f32x2{0.f, 0.f}, p1b = f32x2{0.f, 0.f};
        f32x2 p2a = f32x2{0.f, 0.f}, p2b = f32x2{0.f, 0.f};
        f32x2 p3a = f32x2{0.f, 0.f}, p3b = f32x2{0.f, 0.f};
#define FMQ(Q, K) {                                                  \
        const f32x2 hA = f32x2{Q.x, Q.y};                            \
        const f32x2 hB = f32x2{Q.z, Q.w};                            \
        p0a = hA * f32x2{w0_##K##x, w0_##K##y} + p0a;                \
        p0b = hB * f32x2{w0_##K##z, w0_##K##w} + p0b;                \
        p1a = hA * f32x2{w1_##K##x, w1_##K##y} + p1a;                \
        p1b = hB * f32x2{w1_##K##z, w1_##K##w} + p1b;                \
        p2a = hA * f32x2{w2_##K##x, w2_##K##y} + p2a;                \
        p2b = hB * f32x2{w2_##K##z, w2_##K##w} + p2b;                \
        p3a = hA * f32x2{w3_##K##x, w3_##K##y} + p3a;                \
        p3b = hB * f32x2{w3_##K##z, w3_##K##w} + p3b; }
        FMQ(q0, 0) FMQ(q1, 1) FMQ(q2, 2) FMQ(q3, 3)
        FMQ(q4, 4) FMQ(q5, 5) FMQ(q6, 6)
#undef FMQ
        float p0 = (p0a.x + p0a.y) + (p0b.x + p0b.y);
        float p1 = (p1a.x + p1a.y) + (p1b.x + p1b.y);
        float p2 = (p2a.x + p2a.y) + (p2b.x + p2b.y);
        float p3 = (p3a.x + p3a.y) + (p3b.x + p3b.y);

        // quad butterfly: after xor1+xor2 every lane holds full z0..z3
        p0 += qdpp<0xB1>(p0); p1 += qdpp<0xB1>(p1);   // quad_perm(1,0,3,2)
        p2 += qdpp<0xB1>(p2); p3 += qdpp<0xB1>(p3);
        p0 += qdpp<0x4E>(p0); p1 += qdpp<0x4E>(p1);   // quad_perm(2,3,0,1)
        p2 += qdpp<0x4E>(p2); p3 += qdpp<0x4E>(p3);

        // gates (rows pre-scaled: sigmoid rows by log2e, tanh row by 2log2e)
        const float si = __builtin_amdgcn_rcpf(1.f + __builtin_amdgcn_exp2f(-p0));
        const float sf = __builtin_amdgcn_rcpf(1.f + __builtin_amdgcn_exp2f(-p1));
        const float gg = fmaf(2.f, __builtin_amdgcn_rcpf(1.f + __builtin_amdgcn_exp2f(-p2)), -1.f);
        const float so = __builtin_amdgcn_rcpf(1.f + __builtin_amdgcn_exp2f(-p3));

        // cell update (replicated across the quad's 4 lanes)
        c = fmaf(sf, c, si * gg);
        const float th = fmaf(2.f, __builtin_amdgcn_rcpf(1.f + __builtin_amdgcn_exp2f(c * (-2.f * LOG2E))), -1.f);
        const float hv = so * th;

        float* __restrict__ hn = hbuf[(t + 1) & 1];
        if ((g == 0) & act) hn[j] = hv;
        if (tid < 5) hn[HDIM + tid] = xn;
        __syncthreads();                 // single barrier per step
    }

    // epilogue: out = b_lin + W_lin . h_T   (T_LEN even -> h_T in hbuf[0])
    if (tid == 0) {
        float acc = b_lin[0];
        #pragma unroll
        for (int k = 0; k < HDIM; ++k) acc += W_lin[k] * hbuf[0][k];
        out[0] = acc;
    }
}

extern "C" void kernel_launch(void* const* d_in, const int* in_sizes, int n_in,
                              void* d_out, int out_size, void* d_ws, size_t ws_size,
                              hipStream_t stream) {
    const float* input_seq = (const float*)d_in[0];
    const float* W_ih      = (const float*)d_in[1];
    const float* W_hh      = (const float*)d_in[2];
    const float* b_ih      = (const float*)d_in[3];
    const float* b_hh      = (const float*)d_in[4];
    const float* W_lin     = (const float*)d_in[5];
    const float* b_lin     = (const float*)d_in[6];
    float* out = (float*)d_out;
    float* ws  = (float*)d_ws;           // needs 400*112*4 = 179,200 B

    const int nprep = NROWS * KPAD;
    lstm_prep_kernel<<<(nprep + 255) / 256, 256, 0, stream>>>(W_ih, W_hh, b_ih, b_hh, ws);
    lstm_seq_kernel<<<1, NTHR, 0, stream>>>(input_seq, ws, W_lin, b_lin, out);
}